// Round 1
// baseline (297.493 us; speedup 1.0000x reference)
//
#include <hip/hip_runtime.h>

// Problem constants (SelfAttention_31568009626123)
#define N_TOK 4096
#define DIM   1024

typedef __bf16 bf16x8 __attribute__((ext_vector_type(8)));
typedef float  f32x4  __attribute__((ext_vector_type(4)));

__device__ __forceinline__ unsigned short f2bf(float f) {
  union { float f; unsigned u; } v; v.f = f;
  unsigned u = v.u;
  return (unsigned short)((u + 0x7fffu + ((u >> 16) & 1u)) >> 16);
}
__device__ __forceinline__ float bf2f(unsigned short h) {
  union { unsigned u; float f; } v; v.u = ((unsigned)h) << 16;
  return v.f;
}

// ---------------------------------------------------------------------------
// Elementwise f32 -> bf16 convert (x), 4 elems/thread
// ---------------------------------------------------------------------------
__global__ void cvt_f32_bf16(const float* __restrict__ x,
                             unsigned short* __restrict__ o) {
  int i = (blockIdx.x * 256 + threadIdx.x) * 4;
  float4 v = *(const float4*)(x + i);
  ushort4 r;
  r.x = f2bf(v.x); r.y = f2bf(v.y); r.z = f2bf(v.z); r.w = f2bf(v.w);
  *(ushort4*)(o + i) = r;
}

// ---------------------------------------------------------------------------
// Transpose 1024x1024 f32 -> bf16 (Wt[n][k] = W[k][n]) via 32x32 LDS tile
// ---------------------------------------------------------------------------
__global__ void transpose_cvt(const float* __restrict__ W,
                              unsigned short* __restrict__ Wt) {
  __shared__ float tile[32][33];
  int bx = blockIdx.x * 32;  // col block of W (n)
  int by = blockIdx.y * 32;  // row block of W (k)
  int tx = threadIdx.x, ty = threadIdx.y;
  for (int r = ty; r < 32; r += 8)
    tile[r][tx] = W[(size_t)(by + r) * DIM + bx + tx];
  __syncthreads();
  for (int r = ty; r < 32; r += 8)
    Wt[(size_t)(bx + r) * DIM + by + tx] = f2bf(tile[tx][r]);
}

// ---------------------------------------------------------------------------
// Generic A·B^T MFMA GEMM: C[m][n] = sum_k A[m][k]*B[n][k]  (bf16 in, f32 acc)
// 128x128 block tile, 4 waves (each 64x64 = 4x4 frags of 16x16x32), BK=64.
// LDS row stride 72 elems (144 B) -> 16B-aligned rows, bank-conflict-free-ish.
// EPI: 0 = bf16 store, (acc + bias[col]) * scale   (Q/K projections)
//      1 = bf16 store, acc + bias[row]             (V^T projection)
//      2 = bf16 store, causal mask (col>row -> -inf); skip blocks bn>bm  (S)
//      3 = f32 store, K-loop truncated at (bm+1)*128                     (O)
// ---------------------------------------------------------------------------
#define BK 64
#define LDS_STRIDE 72

template <int EPI>
__global__ void gemm_tn(const unsigned short* __restrict__ A,
                        const unsigned short* __restrict__ B,
                        void* __restrict__ Cout,
                        const float* __restrict__ bias,
                        int K, int lda, int ldb, int ldc, float scale) {
  const int bm = blockIdx.y, bn = blockIdx.x;
  if (EPI == 2 && bn > bm) return;

  __shared__ __align__(16) unsigned short smA[128 * LDS_STRIDE];
  __shared__ __align__(16) unsigned short smB[128 * LDS_STRIDE];

  const int t = threadIdx.x;
  const int lane = t & 63, w = t >> 6;
  const int wm = (w & 1) * 64, wn = (w >> 1) * 64;

  f32x4 acc[4][4] = {};

  const int Keff = (EPI == 3) ? (bm + 1) * 128 : K;
  const unsigned short* Ab = A + (size_t)bm * 128 * lda;
  const unsigned short* Bb = B + (size_t)bn * 128 * ldb;

  const int rA = wm + (lane & 15);
  const int rB = wn + (lane & 15);
  const int kquad = (lane >> 4) << 3;

  for (int k0 = 0; k0 < Keff; k0 += BK) {
    __syncthreads();
#pragma unroll
    for (int c = 0; c < 4; c++) {
      int flat = c * 256 + t;
      int r = flat >> 3, g = flat & 7;
      float4 va = *(const float4*)(Ab + (size_t)r * lda + k0 + g * 8);
      float4 vb = *(const float4*)(Bb + (size_t)r * ldb + k0 + g * 8);
      *(float4*)(&smA[r * LDS_STRIDE + g * 8]) = va;
      *(float4*)(&smB[r * LDS_STRIDE + g * 8]) = vb;
    }
    __syncthreads();

#pragma unroll
    for (int kk = 0; kk < BK; kk += 32) {
      bf16x8 af[4], bfr[4];
      const int kof = kk + kquad;
#pragma unroll
      for (int i = 0; i < 4; i++)
        af[i] = *(const bf16x8*)(&smA[(rA + i * 16) * LDS_STRIDE + kof]);
#pragma unroll
      for (int j = 0; j < 4; j++)
        bfr[j] = *(const bf16x8*)(&smB[(rB + j * 16) * LDS_STRIDE + kof]);
#pragma unroll
      for (int i = 0; i < 4; i++)
#pragma unroll
        for (int j = 0; j < 4; j++)
          acc[i][j] = __builtin_amdgcn_mfma_f32_16x16x32_bf16(af[i], bfr[j],
                                                              acc[i][j], 0, 0, 0);
    }
  }

  // Epilogue.  C/D layout: col = lane&15, row = (lane>>4)*4 + reg.
  float* Cf = (float*)Cout;
  unsigned short* Ch = (unsigned short*)Cout;
  const int colbase = bn * 128 + wn + (lane & 15);
  const int rowbase = bm * 128 + wm + ((lane >> 4) << 2);
#pragma unroll
  for (int i = 0; i < 4; i++) {
#pragma unroll
    for (int j = 0; j < 4; j++) {
      const int gc = colbase + j * 16;
#pragma unroll
      for (int r = 0; r < 4; r++) {
        const int gr = rowbase + i * 16 + r;
        const float v = acc[i][j][r];
        if (EPI == 0) {
          Ch[(size_t)gr * ldc + gc] = f2bf((v + bias[gc]) * scale);
        } else if (EPI == 1) {
          Ch[(size_t)gr * ldc + gc] = f2bf(v + bias[gr]);
        } else if (EPI == 2) {
          Ch[(size_t)gr * ldc + gc] =
              (gc > gr) ? (unsigned short)0xFF80u : f2bf(v);
        } else {
          Cf[(size_t)gr * ldc + gc] = v;
        }
      }
    }
  }
}

// ---------------------------------------------------------------------------
// In-place causal row softmax over bf16 S (row i covers ceil128(i+1) cols;
// masked entries are -inf -> exp = 0, which P@V relies on).
// ---------------------------------------------------------------------------
__global__ void softmax_rows(unsigned short* __restrict__ S) {
  const int row = blockIdx.x;
  const int ncols = ((row >> 7) + 1) << 7;
  const int t = threadIdx.x;
  unsigned short* Srow = S + (size_t)row * N_TOK;

  float vals[16];
  int n = 0;
  float m = -__builtin_inff();
  for (int c = t; c < ncols; c += 256) {
    float s = bf2f(Srow[c]);
    vals[n++] = s;
    m = fmaxf(m, s);
  }
#pragma unroll
  for (int off = 32; off > 0; off >>= 1) m = fmaxf(m, __shfl_xor(m, off));
  __shared__ float redm[4], redl[4];
  if ((t & 63) == 0) redm[t >> 6] = m;
  __syncthreads();
  m = fmaxf(fmaxf(redm[0], redm[1]), fmaxf(redm[2], redm[3]));

  float l = 0.f;
  for (int k = 0; k < n; k++) {
    float e = __expf(vals[k] - m);
    vals[k] = e;
    l += e;
  }
#pragma unroll
  for (int off = 32; off > 0; off >>= 1) l += __shfl_xor(l, off);
  if ((t & 63) == 0) redl[t >> 6] = l;
  __syncthreads();
  l = redl[0] + redl[1] + redl[2] + redl[3];
  const float inv = 1.0f / l;

  n = 0;
  for (int c = t; c < ncols; c += 256) Srow[c] = f2bf(vals[n++] * inv);
}

// ---------------------------------------------------------------------------
// kernel_launch
// inputs: x[4096,1024], W_q[1024,1024], b_q[1024], W_k, b_k, W_v, b_v (f32)
// output: [4096,1024] f32
// ---------------------------------------------------------------------------
extern "C" void kernel_launch(void* const* d_in, const int* in_sizes, int n_in,
                              void* d_out, int out_size, void* d_ws,
                              size_t ws_size, hipStream_t stream) {
  (void)in_sizes; (void)n_in; (void)out_size; (void)ws_size;
  const float* x  = (const float*)d_in[0];
  const float* Wq = (const float*)d_in[1];
  const float* bq = (const float*)d_in[2];
  const float* Wk = (const float*)d_in[3];
  const float* bk = (const float*)d_in[4];
  const float* Wv = (const float*)d_in[5];
  const float* bv = (const float*)d_in[6];
  float* out = (float*)d_out;

  // Workspace layout (bf16 = ushort elems): ~70 MB total
  unsigned short* xb  = (unsigned short*)d_ws;          // 4096x1024
  unsigned short* Wqt = xb  + (size_t)N_TOK * DIM;      // 1024x1024 (W_q^T)
  unsigned short* Wkt = Wqt + (size_t)DIM * DIM;        // 1024x1024
  unsigned short* Wvt = Wkt + (size_t)DIM * DIM;        // 1024x1024
  unsigned short* Qb  = Wvt + (size_t)DIM * DIM;        // 4096x1024 (scaled)
  unsigned short* Kb  = Qb  + (size_t)N_TOK * DIM;      // 4096x1024
  unsigned short* Vtb = Kb  + (size_t)N_TOK * DIM;      // 1024x4096 (V^T)
  unsigned short* Sb  = Vtb + (size_t)N_TOK * DIM;      // 4096x4096 (S then P)

  cvt_f32_bf16<<<(N_TOK * DIM) / 1024, 256, 0, stream>>>(x, xb);
  dim3 tb(32, 8);
  transpose_cvt<<<dim3(32, 32), tb, 0, stream>>>(Wq, Wqt);
  transpose_cvt<<<dim3(32, 32), tb, 0, stream>>>(Wk, Wkt);
  transpose_cvt<<<dim3(32, 32), tb, 0, stream>>>(Wv, Wvt);

  // Q = (x Wq + bq) * 1/sqrt(1024); K = x Wk + bk
  gemm_tn<0><<<dim3(8, 32), 256, 0, stream>>>(xb, Wqt, Qb, bq, DIM, DIM, DIM,
                                              DIM, 0.03125f);
  gemm_tn<0><<<dim3(8, 32), 256, 0, stream>>>(xb, Wkt, Kb, bk, DIM, DIM, DIM,
                                              DIM, 1.0f);
  // V^T[n][m] = sum_k Wvt[n][k] xb[m][k] + bv[n]
  gemm_tn<1><<<dim3(32, 8), 256, 0, stream>>>(Wvt, xb, Vtb, bv, DIM, DIM, DIM,
                                              N_TOK, 1.0f);
  // S = Q K^T (lower-triangle blocks only; diag masked to -inf above diag)
  gemm_tn<2><<<dim3(32, 32), 256, 0, stream>>>(Qb, Kb, Sb, nullptr, DIM, DIM,
                                               DIM, N_TOK, 1.0f);
  softmax_rows<<<N_TOK, 256, 0, stream>>>(Sb);
  // O = P V  (A = P rows, B = V^T rows; K truncated at the diagonal)
  gemm_tn<3><<<dim3(8, 32), 256, 0, stream>>>(Sb, Vtb, out, nullptr, N_TOK,
                                              N_TOK, N_TOK, DIM, 1.0f);
}

// Round 3
// 245.603 us; speedup vs baseline: 1.2113x; 1.2113x over previous
//
#include <hip/hip_runtime.h>

#define N_TOK 4096
#define DIM   1024

typedef __bf16 bf16x8 __attribute__((ext_vector_type(8)));
typedef float  f32x4  __attribute__((ext_vector_type(4)));

__device__ __forceinline__ unsigned short f2bf(float f) {
  union { float f; unsigned u; } v; v.f = f;
  unsigned u = v.u;
  return (unsigned short)((u + 0x7fffu + ((u >> 16) & 1u)) >> 16);
}
__device__ __forceinline__ float bf2f(unsigned short h) {
  union { unsigned u; float f; } v; v.u = ((unsigned)h) << 16;
  return v.f;
}

// ---------------------------------------------------------------------------
// f32 -> bf16 convert (x)
// ---------------------------------------------------------------------------
__global__ void cvt_f32_bf16(const float* __restrict__ x,
                             unsigned short* __restrict__ o) {
  int i = (blockIdx.x * 256 + threadIdx.x) * 4;
  float4 v = *(const float4*)(x + i);
  ushort4 r;
  r.x = f2bf(v.x); r.y = f2bf(v.y); r.z = f2bf(v.z); r.w = f2bf(v.w);
  *(ushort4*)(o + i) = r;
}

// ---------------------------------------------------------------------------
// Transpose 1024x1024 f32 -> bf16 (Wt[n][k] = W[k][n])
// ---------------------------------------------------------------------------
__global__ void transpose_cvt(const float* __restrict__ W,
                              unsigned short* __restrict__ Wt) {
  __shared__ float tile[32][33];
  int bx = blockIdx.x * 32, by = blockIdx.y * 32;
  int tx = threadIdx.x, ty = threadIdx.y;
  for (int r = ty; r < 32; r += 8)
    tile[r][tx] = W[(size_t)(by + r) * DIM + bx + tx];
  __syncthreads();
  for (int r = ty; r < 32; r += 8)
    Wt[(size_t)(bx + r) * DIM + by + tx] = f2bf(tile[tx][r]);
}

// ---------------------------------------------------------------------------
// bf16 transpose: Vt[n][m] = V[m][n], V is [4096 x 1024] with row stride ldv
// ---------------------------------------------------------------------------
__global__ void transpose_bf16(const unsigned short* __restrict__ V, int ldv,
                               unsigned short* __restrict__ Vt, int ldvt) {
  __shared__ unsigned short tile[32][33];
  int bx = blockIdx.x * 32;  // n
  int by = blockIdx.y * 32;  // m
  int tx = threadIdx.x, ty = threadIdx.y;
  for (int r = ty; r < 32; r += 8)
    tile[r][tx] = V[(size_t)(by + r) * ldv + bx + tx];
  __syncthreads();
  for (int r = ty; r < 32; r += 8)
    Vt[(size_t)(bx + r) * ldvt + by + tx] = tile[tx][r];
}

// ---------------------------------------------------------------------------
// Concatenated, pre-scaled bias: ball[0:1024)=bq/32, [1024:2048)=bk, rest=bv
// ---------------------------------------------------------------------------
__global__ void make_bias(const float* __restrict__ bq,
                          const float* __restrict__ bk,
                          const float* __restrict__ bv,
                          float* __restrict__ ball) {
  int i = blockIdx.x * 256 + threadIdx.x;
  float v = (i < 1024) ? bq[i] * 0.03125f
                       : ((i < 2048) ? bk[i - 1024] : bv[i - 2048]);
  ball[i] = v;
}

// ---------------------------------------------------------------------------
// zero-fill f32 output (for atomicAdd epilogue of the O GEMM)
// ---------------------------------------------------------------------------
__global__ void zero_f32(float* __restrict__ p) {
  ((float4*)p)[blockIdx.x * 256 + threadIdx.x] = make_float4(0.f, 0.f, 0.f, 0.f);
}

// ---------------------------------------------------------------------------
// A·B^T MFMA GEMM (round-1 proven inner loop): C[m][n] = sum_k A[m][k]*B[n][k]
// 128x128 tile, 4 waves, BK=64, LDS stride 72.
// EPI 0: concat QKV projection. bf16 store, acc*colscale + ball[gc]
//        (colscale = 1/32 for gc<1024, else 1).
// EPI 2: S = Q K^T. bf16 store, causal mask (col>row -> -inf), skip bn>bm.
// EPI 3: O = P V. split-K over blockIdx.z (1024-wide chunks, clipped to
//        Keff=(bm+1)*128); f32 direct store if single chunk else atomicAdd.
// ---------------------------------------------------------------------------
#define BK 64
#define LDS_STRIDE 72

template <int EPI>
__global__ void gemm_tn(const unsigned short* __restrict__ A,
                        const unsigned short* __restrict__ B,
                        void* __restrict__ Cout,
                        const float* __restrict__ bias,
                        int K, int lda, int ldb, int ldc) {
  int bm, bn, kbeg, kend;
  bool single = true;
  if (EPI == 3) {
    bn = blockIdx.x; bm = blockIdx.y;
    const int Keff = (bm + 1) * 128;
    kbeg = blockIdx.z * 1024;
    if (kbeg >= Keff) return;
    kend = min(kbeg + 1024, Keff);
    single = (Keff <= 1024);
  } else {
    bm = blockIdx.y; bn = blockIdx.x;
    if (EPI == 2 && bn > bm) return;
    kbeg = 0; kend = K;
  }

  __shared__ __align__(16) unsigned short smA[128 * LDS_STRIDE];
  __shared__ __align__(16) unsigned short smB[128 * LDS_STRIDE];

  const int t = threadIdx.x;
  const int lane = t & 63, w = t >> 6;
  const int wm = (w & 1) * 64, wn = (w >> 1) * 64;

  f32x4 acc[4][4] = {};

  const unsigned short* Ab = A + (size_t)bm * 128 * lda;
  const unsigned short* Bb = B + (size_t)bn * 128 * ldb;

  const int rA = wm + (lane & 15);
  const int rB = wn + (lane & 15);
  const int kquad = (lane >> 4) << 3;

  for (int k0 = kbeg; k0 < kend; k0 += BK) {
    __syncthreads();
#pragma unroll
    for (int c = 0; c < 4; c++) {
      int flat = c * 256 + t;
      int r = flat >> 3, g = flat & 7;
      float4 va = *(const float4*)(Ab + (size_t)r * lda + k0 + g * 8);
      float4 vb = *(const float4*)(Bb + (size_t)r * ldb + k0 + g * 8);
      *(float4*)(&smA[r * LDS_STRIDE + g * 8]) = va;
      *(float4*)(&smB[r * LDS_STRIDE + g * 8]) = vb;
    }
    __syncthreads();

#pragma unroll
    for (int kk = 0; kk < BK; kk += 32) {
      bf16x8 af[4], bfr[4];
      const int kof = kk + kquad;
#pragma unroll
      for (int i = 0; i < 4; i++)
        af[i] = *(const bf16x8*)(&smA[(rA + i * 16) * LDS_STRIDE + kof]);
#pragma unroll
      for (int j = 0; j < 4; j++)
        bfr[j] = *(const bf16x8*)(&smB[(rB + j * 16) * LDS_STRIDE + kof]);
#pragma unroll
      for (int i = 0; i < 4; i++)
#pragma unroll
        for (int j = 0; j < 4; j++)
          acc[i][j] = __builtin_amdgcn_mfma_f32_16x16x32_bf16(af[i], bfr[j],
                                                              acc[i][j], 0, 0, 0);
    }
  }

  // Epilogue. C/D layout: col = lane&15, row = (lane>>4)*4 + reg.
  float* Cf = (float*)Cout;
  unsigned short* Ch = (unsigned short*)Cout;
  const int colbase = bn * 128 + wn + (lane & 15);
  const int rowbase = bm * 128 + wm + ((lane >> 4) << 2);
#pragma unroll
  for (int i = 0; i < 4; i++) {
#pragma unroll
    for (int j = 0; j < 4; j++) {
      const int gc = colbase + j * 16;
#pragma unroll
      for (int r = 0; r < 4; r++) {
        const int gr = rowbase + i * 16 + r;
        const float v = acc[i][j][r];
        if (EPI == 0) {
          const float cs = (gc < 1024) ? 0.03125f : 1.0f;
          Ch[(size_t)gr * ldc + gc] = f2bf(v * cs + bias[gc]);
        } else if (EPI == 2) {
          Ch[(size_t)gr * ldc + gc] =
              (gc > gr) ? (unsigned short)0xFF80u : f2bf(v);
        } else {
          if (single)
            Cf[(size_t)gr * ldc + gc] = v;
          else
            atomicAdd(&Cf[(size_t)gr * ldc + gc], v);
        }
      }
    }
  }
}

// ---------------------------------------------------------------------------
// In-place causal row softmax over bf16 S
// ---------------------------------------------------------------------------
__global__ void softmax_rows(unsigned short* __restrict__ S) {
  const int row = blockIdx.x;
  const int ncols = ((row >> 7) + 1) << 7;
  const int t = threadIdx.x;
  unsigned short* Srow = S + (size_t)row * N_TOK;

  float vals[16];
  int n = 0;
  float m = -__builtin_inff();
  for (int c = t; c < ncols; c += 256) {
    float s = bf2f(Srow[c]);
    vals[n++] = s;
    m = fmaxf(m, s);
  }
#pragma unroll
  for (int off = 32; off > 0; off >>= 1) m = fmaxf(m, __shfl_xor(m, off));
  __shared__ float redm[4], redl[4];
  if ((t & 63) == 0) redm[t >> 6] = m;
  __syncthreads();
  m = fmaxf(fmaxf(redm[0], redm[1]), fmaxf(redm[2], redm[3]));

  float l = 0.f;
  for (int k = 0; k < n; k++) {
    float e = __expf(vals[k] - m);
    vals[k] = e;
    l += e;
  }
#pragma unroll
  for (int off = 32; off > 0; off >>= 1) l += __shfl_xor(l, off);
  if ((t & 63) == 0) redl[t >> 6] = l;
  __syncthreads();
  l = redl[0] + redl[1] + redl[2] + redl[3];
  const float inv = 1.0f / l;

  n = 0;
  for (int c = t; c < ncols; c += 256) Srow[c] = f2bf(vals[n++] * inv);
}

// ---------------------------------------------------------------------------
// kernel_launch
// ws layout (ushort elems):
//   [0,4M)    xb [4096x1024]; after concat GEMM, reused as V^T [1024x4096]
//   [4M,7M)   W_all^T = Wq^T | Wk^T | Wv^T  (3072 rows x 1024, contiguous)
//   [7M,19M)  Call [4096x3072] = Q | K | V  (bf16; Q pre-scaled by 1/32)
//   [19M,35M) Sb [4096x4096]  (S then P)
//   [35M,+6K) ball [3072] f32
// ---------------------------------------------------------------------------
extern "C" void kernel_launch(void* const* d_in, const int* in_sizes, int n_in,
                              void* d_out, int out_size, void* d_ws,
                              size_t ws_size, hipStream_t stream) {
  (void)in_sizes; (void)n_in; (void)out_size; (void)ws_size;
  const float* x  = (const float*)d_in[0];
  const float* Wq = (const float*)d_in[1];
  const float* bq = (const float*)d_in[2];
  const float* Wk = (const float*)d_in[3];
  const float* bk = (const float*)d_in[4];
  const float* Wv = (const float*)d_in[5];
  const float* bv = (const float*)d_in[6];
  float* out = (float*)d_out;

  const size_t M1 = (size_t)1024 * 1024;
  unsigned short* xb   = (unsigned short*)d_ws;   // 4M elems; later V^T
  unsigned short* Wt   = xb + 4 * M1;             // 3M elems (3072 x 1024)
  unsigned short* Call = Wt + 3 * M1;             // 12M elems (4096 x 3072)
  unsigned short* Sb   = Call + 12 * M1;          // 16M elems (4096 x 4096)
  float* ball          = (float*)(Sb + 16 * M1);  // 3072 f32

  make_bias<<<12, 256, 0, stream>>>(bq, bk, bv, ball);
  cvt_f32_bf16<<<(N_TOK * DIM) / 1024, 256, 0, stream>>>(x, xb);
  dim3 tb(32, 8);
  transpose_cvt<<<dim3(32, 32), tb, 0, stream>>>(Wq, Wt);
  transpose_cvt<<<dim3(32, 32), tb, 0, stream>>>(Wk, Wt + M1);
  transpose_cvt<<<dim3(32, 32), tb, 0, stream>>>(Wv, Wt + 2 * M1);

  // Call = x @ [Wq|Wk|Wv] + ball (Q cols pre-scaled by 1/32). 768 blocks.
  gemm_tn<0><<<dim3(24, 32), 256, 0, stream>>>(xb, Wt, Call, ball, DIM, DIM,
                                               DIM, 3 * DIM);
  // V^T into the dead xb slot.
  transpose_bf16<<<dim3(32, 128), tb, 0, stream>>>(Call + 2048, 3 * DIM, xb,
                                                   N_TOK);
  // S = Q K^T (Q,K are column slices of Call; lda=ldb=3072).
  gemm_tn<2><<<dim3(32, 32), 256, 0, stream>>>(Call, Call + 1024, Sb, nullptr,
                                               DIM, 3 * DIM, 3 * DIM, N_TOK);
  softmax_rows<<<N_TOK, 256, 0, stream>>>(Sb);
  zero_f32<<<(N_TOK * DIM) / 1024, 256, 0, stream>>>(out);
  // O = P V, split-K over z (4 chunks of 1024).
  gemm_tn<3><<<dim3(8, 32, 4), 256, 0, stream>>>(Sb, xb, out, nullptr, N_TOK,
                                                 N_TOK, N_TOK, DIM);
}

// Round 4
// 243.304 us; speedup vs baseline: 1.2227x; 1.0094x over previous
//
#include <hip/hip_runtime.h>

#define N_TOK 4096
#define DIM   1024

typedef __bf16 bf16x8 __attribute__((ext_vector_type(8)));
typedef float  f32x4  __attribute__((ext_vector_type(4)));

__device__ __forceinline__ unsigned short f2bf(float f) {
  union { float f; unsigned u; } v; v.f = f;
  unsigned u = v.u;
  return (unsigned short)((u + 0x7fffu + ((u >> 16) & 1u)) >> 16);
}
__device__ __forceinline__ float bf2f(unsigned short h) {
  union { unsigned u; float f; } v; v.u = ((unsigned)h) << 16;
  return v.f;
}

// async global->LDS, 16 B/lane: lane's data lands at (uniform lds base) + lane*16
__device__ __forceinline__ void gll16(const unsigned short* g,
                                      unsigned short* l) {
  __builtin_amdgcn_global_load_lds(
      (const __attribute__((address_space(1))) unsigned int*)g,
      (__attribute__((address_space(3))) unsigned int*)l, 16, 0, 0);
}

// ---------------------------------------------------------------------------
// f32 -> bf16 convert (x)
// ---------------------------------------------------------------------------
__global__ void cvt_f32_bf16(const float* __restrict__ x,
                             unsigned short* __restrict__ o) {
  int i = (blockIdx.x * 256 + threadIdx.x) * 4;
  float4 v = *(const float4*)(x + i);
  ushort4 r;
  r.x = f2bf(v.x); r.y = f2bf(v.y); r.z = f2bf(v.z); r.w = f2bf(v.w);
  *(ushort4*)(o + i) = r;
}

// ---------------------------------------------------------------------------
// Transpose 1024x1024 f32 -> bf16 (Wt[n][k] = W[k][n])
// ---------------------------------------------------------------------------
__global__ void transpose_cvt(const float* __restrict__ W,
                              unsigned short* __restrict__ Wt) {
  __shared__ float tile[32][33];
  int bx = blockIdx.x * 32, by = blockIdx.y * 32;
  int tx = threadIdx.x, ty = threadIdx.y;
  for (int r = ty; r < 32; r += 8)
    tile[r][tx] = W[(size_t)(by + r) * DIM + bx + tx];
  __syncthreads();
  for (int r = ty; r < 32; r += 8)
    Wt[(size_t)(bx + r) * DIM + by + tx] = f2bf(tile[tx][r]);
}

// ---------------------------------------------------------------------------
// bf16 transpose: Vt[n][m] = V[m][n]
// ---------------------------------------------------------------------------
__global__ void transpose_bf16(const unsigned short* __restrict__ V, int ldv,
                               unsigned short* __restrict__ Vt, int ldvt) {
  __shared__ unsigned short tile[32][33];
  int bx = blockIdx.x * 32;  // n
  int by = blockIdx.y * 32;  // m
  int tx = threadIdx.x, ty = threadIdx.y;
  for (int r = ty; r < 32; r += 8)
    tile[r][tx] = V[(size_t)(by + r) * ldv + bx + tx];
  __syncthreads();
  for (int r = ty; r < 32; r += 8)
    Vt[(size_t)(bx + r) * ldvt + by + tx] = tile[tx][r];
}

// ---------------------------------------------------------------------------
// Concatenated, pre-scaled bias: ball[0:1024)=bq/32, [1024:2048)=bk, rest=bv
// ---------------------------------------------------------------------------
__global__ void make_bias(const float* __restrict__ bq,
                          const float* __restrict__ bk,
                          const float* __restrict__ bv,
                          float* __restrict__ ball) {
  int i = blockIdx.x * 256 + threadIdx.x;
  float v = (i < 1024) ? bq[i] * 0.03125f
                       : ((i < 2048) ? bk[i - 1024] : bv[i - 2048]);
  ball[i] = v;
}

// ---------------------------------------------------------------------------
// zero-fill f32 output (for atomicAdd epilogue of the O GEMM)
// ---------------------------------------------------------------------------
__global__ void zero_f32(float* __restrict__ p) {
  ((float4*)p)[blockIdx.x * 256 + threadIdx.x] = make_float4(0.f, 0.f, 0.f, 0.f);
}

// ---------------------------------------------------------------------------
// A·B^T MFMA GEMM: C[m][n] = sum_k A[m][k]*B[n][k]
// 128x128 tile, 4 waves, BK=64. Staging: global_load_lds width=16 into
// contiguous LDS 128x64 (m97 layout): wave w stages rows w*32+m*8..+8,
// lane supplies global (row r0+lane/8, k-chunk (lane&7)*8), landing at
// lds base + lane*16B == [row][k-chunk]. No padding (gll constraint).
// EPI 0: concat QKV projection. bf16 store, acc*colscale + ball[gc].
// EPI 2: S = Q K^T. bf16 store, causal mask, skip bn>bm.
// EPI 3: O = P V. split-K over blockIdx.z; direct store / atomicAdd.
// ---------------------------------------------------------------------------
#define BK 64

template <int EPI>
__global__ void gemm_tn(const unsigned short* __restrict__ A,
                        const unsigned short* __restrict__ B,
                        void* __restrict__ Cout,
                        const float* __restrict__ bias,
                        int K, int lda, int ldb, int ldc) {
  int bm, bn, kbeg, kend;
  bool single = true;
  if (EPI == 3) {
    bn = blockIdx.x; bm = blockIdx.y;
    const int Keff = (bm + 1) * 128;
    kbeg = blockIdx.z * 1024;
    if (kbeg >= Keff) return;
    kend = min(kbeg + 1024, Keff);
    single = (Keff <= 1024);
  } else {
    bm = blockIdx.y; bn = blockIdx.x;
    if (EPI == 2 && bn > bm) return;
    kbeg = 0; kend = K;
  }

  __shared__ __align__(16) unsigned short smA[128 * 64];
  __shared__ __align__(16) unsigned short smB[128 * 64];

  const int t = threadIdx.x;
  const int lane = t & 63, w = t >> 6;
  const int wm = (w & 1) * 64, wn = (w >> 1) * 64;

  f32x4 acc[4][4] = {};

  const unsigned short* Ab = A + (size_t)bm * 128 * lda;
  const unsigned short* Bb = B + (size_t)bn * 128 * ldb;

  const int rA = wm + (lane & 15);
  const int rB = wn + (lane & 15);
  const int kquad = (lane >> 4) << 3;

  // staging source pointers (per-lane): row lr = lane>>3, k-chunk (lane&7)*8
  const int lr = lane >> 3;
  const int g8 = (lane & 7) << 3;
  const unsigned short* pa = Ab + (size_t)lr * lda + g8 + kbeg;
  const unsigned short* pb = Bb + (size_t)lr * ldb + g8 + kbeg;

  for (int k0 = kbeg; k0 < kend; k0 += BK) {
    __syncthreads();
#pragma unroll
    for (int m = 0; m < 4; m++) {
      const int r0 = (w << 5) + (m << 3);  // wave-uniform LDS row base
      gll16(pa + (size_t)r0 * lda, smA + r0 * 64);
      gll16(pb + (size_t)r0 * ldb, smB + r0 * 64);
    }
    pa += BK; pb += BK;
    __syncthreads();  // drains vmcnt -> tiles resident

#pragma unroll
    for (int kk = 0; kk < BK; kk += 32) {
      bf16x8 af[4], bfr[4];
      const int kof = kk + kquad;
#pragma unroll
      for (int i = 0; i < 4; i++)
        af[i] = *(const bf16x8*)(&smA[(rA + i * 16) * 64 + kof]);
#pragma unroll
      for (int j = 0; j < 4; j++)
        bfr[j] = *(const bf16x8*)(&smB[(rB + j * 16) * 64 + kof]);
#pragma unroll
      for (int i = 0; i < 4; i++)
#pragma unroll
        for (int j = 0; j < 4; j++)
          acc[i][j] = __builtin_amdgcn_mfma_f32_16x16x32_bf16(af[i], bfr[j],
                                                              acc[i][j], 0, 0, 0);
    }
  }

  // Epilogue. C/D layout: col = lane&15, row = (lane>>4)*4 + reg.
  float* Cf = (float*)Cout;
  unsigned short* Ch = (unsigned short*)Cout;
  const int colbase = bn * 128 + wn + (lane & 15);
  const int rowbase = bm * 128 + wm + ((lane >> 4) << 2);
#pragma unroll
  for (int i = 0; i < 4; i++) {
#pragma unroll
    for (int j = 0; j < 4; j++) {
      const int gc = colbase + j * 16;
#pragma unroll
      for (int r = 0; r < 4; r++) {
        const int gr = rowbase + i * 16 + r;
        const float v = acc[i][j][r];
        if (EPI == 0) {
          const float cs = (gc < 1024) ? 0.03125f : 1.0f;
          Ch[(size_t)gr * ldc + gc] = f2bf(v * cs + bias[gc]);
        } else if (EPI == 2) {
          Ch[(size_t)gr * ldc + gc] =
              (gc > gr) ? (unsigned short)0xFF80u : f2bf(v);
        } else {
          if (single)
            Cf[(size_t)gr * ldc + gc] = v;
          else
            atomicAdd(&Cf[(size_t)gr * ldc + gc], v);
        }
      }
    }
  }
}

// ---------------------------------------------------------------------------
// In-place causal row softmax over bf16 S
// ---------------------------------------------------------------------------
__global__ void softmax_rows(unsigned short* __restrict__ S) {
  const int row = blockIdx.x;
  const int ncols = ((row >> 7) + 1) << 7;
  const int t = threadIdx.x;
  unsigned short* Srow = S + (size_t)row * N_TOK;

  float vals[16];
  int n = 0;
  float m = -__builtin_inff();
  for (int c = t; c < ncols; c += 256) {
    float s = bf2f(Srow[c]);
    vals[n++] = s;
    m = fmaxf(m, s);
  }
#pragma unroll
  for (int off = 32; off > 0; off >>= 1) m = fmaxf(m, __shfl_xor(m, off));
  __shared__ float redm[4], redl[4];
  if ((t & 63) == 0) redm[t >> 6] = m;
  __syncthreads();
  m = fmaxf(fmaxf(redm[0], redm[1]), fmaxf(redm[2], redm[3]));

  float l = 0.f;
  for (int k = 0; k < n; k++) {
    float e = __expf(vals[k] - m);
    vals[k] = e;
    l += e;
  }
#pragma unroll
  for (int off = 32; off > 0; off >>= 1) l += __shfl_xor(l, off);
  if ((t & 63) == 0) redl[t >> 6] = l;
  __syncthreads();
  l = redl[0] + redl[1] + redl[2] + redl[3];
  const float inv = 1.0f / l;

  n = 0;
  for (int c = t; c < ncols; c += 256) Srow[c] = f2bf(vals[n++] * inv);
}

// ---------------------------------------------------------------------------
// kernel_launch — ws layout (ushort elems):
//   [0,4M)    xb [4096x1024]; after concat GEMM, reused as V^T [1024x4096]
//   [4M,7M)   W_all^T = Wq^T | Wk^T | Wv^T  (3072 x 1024)
//   [7M,19M)  Call [4096x3072] = Q | K | V  (Q pre-scaled by 1/32)
//   [19M,35M) Sb [4096x4096]  (S then P)
//   [35M,+)   ball [3072] f32
// ---------------------------------------------------------------------------
extern "C" void kernel_launch(void* const* d_in, const int* in_sizes, int n_in,
                              void* d_out, int out_size, void* d_ws,
                              size_t ws_size, hipStream_t stream) {
  (void)in_sizes; (void)n_in; (void)out_size; (void)ws_size;
  const float* x  = (const float*)d_in[0];
  const float* Wq = (const float*)d_in[1];
  const float* bq = (const float*)d_in[2];
  const float* Wk = (const float*)d_in[3];
  const float* bk = (const float*)d_in[4];
  const float* Wv = (const float*)d_in[5];
  const float* bv = (const float*)d_in[6];
  float* out = (float*)d_out;

  const size_t M1 = (size_t)1024 * 1024;
  unsigned short* xb   = (unsigned short*)d_ws;   // 4M elems; later V^T
  unsigned short* Wt   = xb + 4 * M1;             // 3M elems
  unsigned short* Call = Wt + 3 * M1;             // 12M elems
  unsigned short* Sb   = Call + 12 * M1;          // 16M elems
  float* ball          = (float*)(Sb + 16 * M1);  // 3072 f32

  make_bias<<<12, 256, 0, stream>>>(bq, bk, bv, ball);
  cvt_f32_bf16<<<(N_TOK * DIM) / 1024, 256, 0, stream>>>(x, xb);
  dim3 tb(32, 8);
  transpose_cvt<<<dim3(32, 32), tb, 0, stream>>>(Wq, Wt);
  transpose_cvt<<<dim3(32, 32), tb, 0, stream>>>(Wk, Wt + M1);
  transpose_cvt<<<dim3(32, 32), tb, 0, stream>>>(Wv, Wt + 2 * M1);

  // Call = x @ [Wq|Wk|Wv] + ball. 768 blocks (3 blocks/CU).
  gemm_tn<0><<<dim3(24, 32), 256, 0, stream>>>(xb, Wt, Call, ball, DIM, DIM,
                                               DIM, 3 * DIM);
  // V^T into the dead xb slot.
  transpose_bf16<<<dim3(32, 128), tb, 0, stream>>>(Call + 2048, 3 * DIM, xb,
                                                   N_TOK);
  // S = Q K^T (Q,K are column slices of Call).
  gemm_tn<2><<<dim3(32, 32), 256, 0, stream>>>(Call, Call + 1024, Sb, nullptr,
                                               DIM, 3 * DIM, 3 * DIM, N_TOK);
  softmax_rows<<<N_TOK, 256, 0, stream>>>(Sb);
  zero_f32<<<(N_TOK * DIM) / 1024, 256, 0, stream>>>(out);
  // O = P V, split-K over z (4 chunks of 1024).
  gemm_tn<3><<<dim3(8, 32, 4), 256, 0, stream>>>(Sb, xb, out, nullptr, N_TOK,
                                                 N_TOK, N_TOK, DIM);
}